// Round 8
// baseline (318.947 us; speedup 1.0000x reference)
//
#include <hip/hip_runtime.h>
#include <hip/hip_cooperative_groups.h>

namespace cg = cooperative_groups;

#define NG 48
#define NT 6                   // 4 A tiles per axis (8 cells)
#define NTILES (NT * NT * NT)  // 216
#define CAP 1536               // max atoms per (type,tile); expected max ~1010
#define LISTS_OFF 4096
#define COPIES_OFF (2u << 20)            // 2 MiB (lists end at ~1.99 MB)
#define GRID_FLOATS (3 * NG * NG * NG)   // 331776 floats per partial copy
#define MAXSEG 8
#define GBLOCKS 1024

__device__ __forceinline__ float type_r(int type) {
    return (type == 0) ? 1.7f : ((type == 1) ? 1.55f : 1.52f);
}

// ---------------- fused cooperative kernel: zero + bin + gather + reduce ----
__global__ __launch_bounds__(256, 4) void fused_kernel(
    const float* __restrict__ vC,
    const float* __restrict__ vN,
    const float* __restrict__ vO,
    int* __restrict__ cnt,
    unsigned short* __restrict__ lists,
    float* __restrict__ copies,
    float* __restrict__ out,
    int natoms, int nseg)
{
    cg::grid_group grid = cg::this_grid();
    const int tid = threadIdx.x;
    const int bid = blockIdx.x;

    __shared__ int lcnt[NTILES];
    __shared__ int lbase[NTILES];
    __shared__ int lfill[NTILES];
    __shared__ float4 sa[256];

    // ---- phase 0: zero the per-(type,tile) counters ----
    {
        const int idx = bid * 256 + tid;
        if (idx < 3 * NTILES) cnt[idx] = 0;
    }
    grid.sync();

    // ---- phase 1: bin (two-level histogram, one unit = 256 atoms x type) ----
    const int nchunk = (natoms + 255) / 256;
    const int nbun   = 3 * nchunk;
    for (int u = bid; u < nbun; u += GBLOCKS) {
        const int type  = u / nchunk;
        const int chunk = u - type * nchunk;
        const int atom  = chunk * 256 + tid;
        const float r = type_r(type);
        const float b = 1.5f * r + 1e-3f;
        const float* __restrict__ vecs = (type == 0) ? vC : ((type == 1) ? vN : vO);

        if (tid < NTILES) { lcnt[tid] = 0; lfill[tid] = 0; }
        __syncthreads();

        int x0 = 1, x1 = 0, y0 = 1, y1 = 0, z0 = 1, z1 = 0;
        if (atom < natoms) {
            const float vx = vecs[3 * atom + 0] + 23.5f;  // vec = raw + 24 - 0.5
            const float vy = vecs[3 * atom + 1] + 23.5f;
            const float vz = vecs[3 * atom + 2] + 23.5f;
            // tile t intersects halo iff 4t > v - b - 3.5 and 4t < v + b
            x0 = max(0,      (int)floorf((vx - 3.5f - b) * 0.25f) + 1);
            x1 = min(NT - 1, (int)ceilf ((vx + b)        * 0.25f) - 1);
            y0 = max(0,      (int)floorf((vy - 3.5f - b) * 0.25f) + 1);
            y1 = min(NT - 1, (int)ceilf ((vy + b)        * 0.25f) - 1);
            z0 = max(0,      (int)floorf((vz - 3.5f - b) * 0.25f) + 1);
            z1 = min(NT - 1, (int)ceilf ((vz + b)        * 0.25f) - 1);
        }
        const bool has = (x0 <= x1) & (y0 <= y1) & (z0 <= z1);

        if (has)
            for (int tx = x0; tx <= x1; ++tx)
                for (int ty = y0; ty <= y1; ++ty)
                    for (int tz = z0; tz <= z1; ++tz)
                        atomicAdd(&lcnt[(tx * NT + ty) * NT + tz], 1);  // LDS
        __syncthreads();

        if (tid < NTILES && lcnt[tid] > 0)
            lbase[tid] = atomicAdd(&cnt[type * NTILES + tid], lcnt[tid]);
        __syncthreads();

        if (has)
            for (int tx = x0; tx <= x1; ++tx)
                for (int ty = y0; ty <= y1; ++ty)
                    for (int tz = z0; tz <= z1; ++tz) {
                        const int tl = (tx * NT + ty) * NT + tz;
                        const int p  = lbase[tl] + atomicAdd(&lfill[tl], 1);
                        if (p < CAP)
                            lists[(size_t)(type * NTILES + tl) * CAP + p] =
                                (unsigned short)atom;
                    }
        __syncthreads();   // protect LDS reuse by next unit
    }
    grid.sync();

    // ---- phase 2: gather (unit = (tile, segment, type)), permuted spread ----
    const int ngun = NTILES * nseg * 3;
    for (int uu = bid; uu < ngun; uu += GBLOCKS) {
        const int u = (int)(((long long)uu * 1579) % ngun);  // gcd(1579, 2^a*3^b)=1
        const int type = u / (NTILES * nseg);
        const int rem  = u - type * (NTILES * nseg);
        const int t    = rem / nseg;
        const int s    = rem - t * nseg;

        const float r = type_r(type);
        const float* __restrict__ vecs = (type == 0) ? vC : ((type == 1) ? vN : vO);

        const int tx = t / (NT * NT);
        const int ty = (t / NT) % NT;
        const int tz = t % NT;

        const int lx = tid >> 6;          // 0..3
        const int ly = (tid >> 3) & 7;
        const int lz = tid & 7;

        const float b      = 1.5f * r;
        const float r15sq  = b * b;
        const float rr     = r * r;
        const float E2     = 7.3890562f;
        const float c2a    = 4.0f / (E2 * rr);
        const float c2b    = 12.0f / (E2 * r);
        const float c2c    = 9.0f / E2;
        const float n2orr  = -2.0f / rr;

        const float px0 = 0.5f * (float)(tx * 8 + lx);
        const float px1 = px0 + 2.0f;
        const float py  = 0.5f * (float)(ty * 8 + ly);
        const float pz  = 0.5f * (float)(tz * 8 + lz);

        const int lt = type * NTILES + t;
        const int n  = min(cnt[lt], CAP);
        const int len   = (n + nseg - 1) / nseg;
        const int start = s * len;
        const int end   = min(n, start + len);
        const unsigned short* __restrict__ lst = lists + (size_t)lt * CAP;

        float acc0 = 0.0f, acc1 = 0.0f;

        for (int base = start; base < end; base += 256) {
            const int m = min(256, end - base);
            if (tid < m) {
                const int idx = (int)lst[base + tid];
                sa[tid] = make_float4(vecs[3 * idx + 0] + 23.5f,
                                      vecs[3 * idx + 1] + 23.5f,
                                      vecs[3 * idx + 2] + 23.5f, 0.0f);
            }
            __syncthreads();

            for (int j = 0; j < m; ++j) {
                const float4 a = sa[j];               // one b128 LDS broadcast
                const float dy  = a.y - py;
                const float dz  = a.z - pz;
                const float syz = fmaf(dy, dy, dz * dz);
                const float dx0 = a.x - px0;
                const float d2a = fmaf(dx0, dx0, syz);
                const float dx1 = a.x - px1;
                const float d2b = fmaf(dx1, dx1, syz);
                const bool h0 = d2a < r15sq;
                const bool h1 = d2b < r15sq;
                if (__ballot(h0 | h1) == 0ull) continue;   // whole-wave miss cull
                if (h0) {
                    const float d = sqrtf(d2a);
                    acc0 += (d < r) ? __expf(n2orr * d2a)
                                    : fmaf(c2a, d2a, fmaf(-c2b, d, c2c));
                }
                if (h1) {
                    const float d = sqrtf(d2b);
                    acc1 += (d < r) ? __expf(n2orr * d2b)
                                    : fmaf(c2a, d2b, fmaf(-c2b, d, c2c));
                }
            }
            __syncthreads();
        }

        const int X0 = tx * 8 + lx;
        const int Y  = ty * 8 + ly;
        const int Z  = tz * 8 + lz;
        float* __restrict__ o = copies + (size_t)s * GRID_FLOATS
                                       + (size_t)type * NG * NG * NG;
        o[((X0      * NG) + Y) * NG + Z] = acc0;
        o[(((X0 + 4) * NG) + Y) * NG + Z] = acc1;
    }
    grid.sync();

    // ---- phase 3: reduce partial copies -> out ----
    const int nrun = GRID_FLOATS / 4 / 256;   // 324
    for (int u = bid; u < nrun; u += GBLOCKS) {
        const int i4 = u * 256 + tid;
        const float4* __restrict__ c = (const float4*)copies;
        float4 acc = c[i4];
        for (int s = 1; s < nseg; ++s) {
            const float4 v = c[(size_t)s * (GRID_FLOATS / 4) + i4];
            acc.x += v.x; acc.y += v.y; acc.z += v.z; acc.w += v.w;
        }
        ((float4*)out)[i4] = acc;
    }
}

// ---------------- fallback path (identical to R7): 4 dispatches -------------
__global__ __launch_bounds__(256) void bin_kernel(
    const float* __restrict__ vC, const float* __restrict__ vN,
    const float* __restrict__ vO, int* __restrict__ cnt,
    unsigned short* __restrict__ lists, int natoms)
{
    const int type = blockIdx.y;
    const float r = type_r(type);
    const float b = 1.5f * r + 1e-3f;
    const float* __restrict__ vecs = (type == 0) ? vC : ((type == 1) ? vN : vO);
    const int tid  = threadIdx.x;
    const int atom = blockIdx.x * 256 + tid;

    __shared__ int lcnt[NTILES];
    __shared__ int lbase[NTILES];
    __shared__ int lfill[NTILES];
    if (tid < NTILES) { lcnt[tid] = 0; lfill[tid] = 0; }
    __syncthreads();

    int x0 = 1, x1 = 0, y0 = 1, y1 = 0, z0 = 1, z1 = 0;
    if (atom < natoms) {
        const float vx = vecs[3 * atom + 0] + 23.5f;
        const float vy = vecs[3 * atom + 1] + 23.5f;
        const float vz = vecs[3 * atom + 2] + 23.5f;
        x0 = max(0,      (int)floorf((vx - 3.5f - b) * 0.25f) + 1);
        x1 = min(NT - 1, (int)ceilf ((vx + b)        * 0.25f) - 1);
        y0 = max(0,      (int)floorf((vy - 3.5f - b) * 0.25f) + 1);
        y1 = min(NT - 1, (int)ceilf ((vy + b)        * 0.25f) - 1);
        z0 = max(0,      (int)floorf((vz - 3.5f - b) * 0.25f) + 1);
        z1 = min(NT - 1, (int)ceilf ((vz + b)        * 0.25f) - 1);
    }
    const bool has = (x0 <= x1) & (y0 <= y1) & (z0 <= z1);
    if (has)
        for (int tx = x0; tx <= x1; ++tx)
            for (int ty = y0; ty <= y1; ++ty)
                for (int tz = z0; tz <= z1; ++tz)
                    atomicAdd(&lcnt[(tx * NT + ty) * NT + tz], 1);
    __syncthreads();
    if (tid < NTILES && lcnt[tid] > 0)
        lbase[tid] = atomicAdd(&cnt[type * NTILES + tid], lcnt[tid]);
    __syncthreads();
    if (has)
        for (int tx = x0; tx <= x1; ++tx)
            for (int ty = y0; ty <= y1; ++ty)
                for (int tz = z0; tz <= z1; ++tz) {
                    const int tl = (tx * NT + ty) * NT + tz;
                    const int p  = lbase[tl] + atomicAdd(&lfill[tl], 1);
                    if (p < CAP)
                        lists[(size_t)(type * NTILES + tl) * CAP + p] =
                            (unsigned short)atom;
                }
}

__global__ __launch_bounds__(256) void gather_seg(
    const float* __restrict__ vC, const float* __restrict__ vN,
    const float* __restrict__ vO, const int* __restrict__ cnt,
    const unsigned short* __restrict__ lists, float* __restrict__ copies,
    int nseg)
{
    const int type = blockIdx.y;
    const float r = type_r(type);
    const float* __restrict__ vecs = (type == 0) ? vC : ((type == 1) ? vN : vO);
    const int t = blockIdx.x / nseg;
    const int s = blockIdx.x - t * nseg;
    const int tx = t / (NT * NT);
    const int ty = (t / NT) % NT;
    const int tz = t % NT;
    const int tid = threadIdx.x;
    const int lx  = tid >> 6;
    const int ly  = (tid >> 3) & 7;
    const int lz  = tid & 7;
    const float b      = 1.5f * r;
    const float r15sq  = b * b;
    const float rr     = r * r;
    const float E2     = 7.3890562f;
    const float c2a    = 4.0f / (E2 * rr);
    const float c2b    = 12.0f / (E2 * r);
    const float c2c    = 9.0f / E2;
    const float n2orr  = -2.0f / rr;
    const float px0 = 0.5f * (float)(tx * 8 + lx);
    const float px1 = px0 + 2.0f;
    const float py  = 0.5f * (float)(ty * 8 + ly);
    const float pz  = 0.5f * (float)(tz * 8 + lz);
    __shared__ float4 sa[256];
    const int lt = type * NTILES + t;
    const int n  = min(cnt[lt], CAP);
    const int len   = (n + nseg - 1) / nseg;
    const int start = s * len;
    const int end   = min(n, start + len);
    const unsigned short* __restrict__ lst = lists + (size_t)lt * CAP;
    float acc0 = 0.0f, acc1 = 0.0f;
    for (int base = start; base < end; base += 256) {
        const int m = min(256, end - base);
        if (tid < m) {
            const int idx = (int)lst[base + tid];
            sa[tid] = make_float4(vecs[3 * idx + 0] + 23.5f,
                                  vecs[3 * idx + 1] + 23.5f,
                                  vecs[3 * idx + 2] + 23.5f, 0.0f);
        }
        __syncthreads();
        for (int j = 0; j < m; ++j) {
            const float4 a = sa[j];
            const float dy  = a.y - py;
            const float dz  = a.z - pz;
            const float syz = fmaf(dy, dy, dz * dz);
            const float dx0 = a.x - px0;
            const float d2a = fmaf(dx0, dx0, syz);
            const float dx1 = a.x - px1;
            const float d2b = fmaf(dx1, dx1, syz);
            const bool h0 = d2a < r15sq;
            const bool h1 = d2b < r15sq;
            if (__ballot(h0 | h1) == 0ull) continue;
            if (h0) {
                const float d = sqrtf(d2a);
                acc0 += (d < r) ? __expf(n2orr * d2a)
                                : fmaf(c2a, d2a, fmaf(-c2b, d, c2c));
            }
            if (h1) {
                const float d = sqrtf(d2b);
                acc1 += (d < r) ? __expf(n2orr * d2b)
                                : fmaf(c2a, d2b, fmaf(-c2b, d, c2c));
            }
        }
        __syncthreads();
    }
    const int X0 = tx * 8 + lx;
    const int Y  = ty * 8 + ly;
    const int Z  = tz * 8 + lz;
    float* __restrict__ o = copies + (size_t)s * GRID_FLOATS
                                   + (size_t)type * NG * NG * NG;
    o[((X0      * NG) + Y) * NG + Z] = acc0;
    o[(((X0 + 4) * NG) + Y) * NG + Z] = acc1;
}

__global__ __launch_bounds__(256) void reduce_kernel(
    const float* __restrict__ copies, float* __restrict__ out, int nseg)
{
    const int i4 = blockIdx.x * 256 + threadIdx.x;
    if (i4 >= GRID_FLOATS / 4) return;
    const float4* __restrict__ c = (const float4*)copies;
    float4 acc = c[i4];
    for (int s = 1; s < nseg; ++s) {
        const float4 v = c[(size_t)s * (GRID_FLOATS / 4) + i4];
        acc.x += v.x; acc.y += v.y; acc.z += v.z; acc.w += v.w;
    }
    ((float4*)out)[i4] = acc;
}

extern "C" void kernel_launch(void* const* d_in, const int* in_sizes, int n_in,
                              void* d_out, int out_size, void* d_ws, size_t ws_size,
                              hipStream_t stream) {
    const float* vC = (const float*)d_in[0];
    const float* vN = (const float*)d_in[1];
    const float* vO = (const float*)d_in[2];
    float* out = (float*)d_out;

    int* cnt = (int*)d_ws;
    unsigned short* lists = (unsigned short*)((char*)d_ws + LISTS_OFF);
    float* copies = (float*)((char*)d_ws + COPIES_OFF);

    const size_t copy_bytes = (size_t)GRID_FLOATS * sizeof(float);
    long avail = (long)((ws_size - COPIES_OFF) / copy_bytes);
    int nseg = (int)(avail < 1 ? 1 : (avail > MAXSEG ? MAXSEG : avail));

    int natoms = in_sizes[0] / 3;   // 16384

    void* args[] = { (void*)&vC, (void*)&vN, (void*)&vO, (void*)&cnt,
                     (void*)&lists, (void*)&copies, (void*)&out,
                     (void*)&natoms, (void*)&nseg };
    hipError_t e = hipLaunchCooperativeKernel((const void*)fused_kernel,
                                              dim3(GBLOCKS), dim3(256),
                                              args, 0, stream);
    if (e != hipSuccess) {
        // fallback: R7's 4-dispatch path
        hipMemsetAsync(cnt, 0, 3 * NTILES * sizeof(int), stream);
        dim3 bgrid((natoms + 255) / 256, 3, 1);
        bin_kernel<<<bgrid, 256, 0, stream>>>(vC, vN, vO, cnt, lists, natoms);
        dim3 ggrid(NTILES * nseg, 3, 1);
        gather_seg<<<ggrid, 256, 0, stream>>>(vC, vN, vO, cnt, lists, copies, nseg);
        dim3 rgrid((GRID_FLOATS / 4 + 255) / 256, 1, 1);
        reduce_kernel<<<rgrid, 256, 0, stream>>>(copies, out, nseg);
    }
}